// Round 7
// baseline (88.849 us; speedup 1.0000x reference)
//
#include <hip/hip_runtime.h>
#include <math.h>

// Problem constants (fixed by reference: inp (4,16,32,32) f32, weight (64,144) f32)
constexpr int F_IN   = 144;   // 16 ch * 9 taps
constexpr int F_OUT  = 64;
constexpr int H_IMG  = 32;
constexpr int W_IMG  = 32;
constexpr int NPIX   = 4 * H_IMG * W_IMG;  // 4096
constexpr int PPB    = 8;                  // pixels per block (1 wave each)
constexpr int NTHR   = PPB * 64;           // 512
#define MAX_SPIKE 100.0f

// ---------------------------------------------------------------------------
// Weight quantization (validated r2-r6; tanhf == same ulp class as np f32 ref,
// r6 confirmed passing at the 0.0039 comparison floor).
// alpha = tanhf(max|w|) == max tanhf(|w|) (monotone, w >= 0).
// rintf = half-to-even like np.round; mul-then-div mirrors np rounding.
// ---------------------------------------------------------------------------
__global__ __launch_bounds__(256) void quant_fused_kernel(
    const float* __restrict__ w,
    float* __restrict__ wqT)   // (144,64) transposed
{
#pragma clang fp contract(off)
    __shared__ float wred[4];
    const int tid = threadIdx.x;

    float m = 0.f;
    {
        const float4* w4 = (const float4*)w;
        for (int i = tid; i < (F_OUT * F_IN) / 4; i += 256) {
            const float4 v = w4[i];
            m = fmaxf(m, fmaxf(fmaxf(fabsf(v.x), fabsf(v.y)),
                               fmaxf(fabsf(v.z), fabsf(v.w))));
        }
    }
    for (int s = 32; s > 0; s >>= 1)
        m = fmaxf(m, __shfl_xor(m, s, 64));
    if ((tid & 63) == 0) wred[tid >> 6] = m;
    __syncthreads();
    const float mw = fmaxf(fmaxf(wred[0], wred[1]), fmaxf(wred[2], wred[3]));
    const float alpha = tanhf(mw);

    const int i = blockIdx.x * 256 + tid;   // 36*256 = 9216 exactly
    const int o = i / F_IN;
    const int f = i - o * F_IN;
    const float t = tanhf(w[i]);
    float x = t / alpha;                       // f32 divide (mirrors np)
    x = fminf(fmaxf(x, -1.f), 1.f) * 127.f;    // clip then *qmax
    const float r = rintf(x);                  // round half-to-even
    wqT[f * F_OUT + o] = r * alpha / 127.f;    // mul then div (mirrors np)
}

// ---- helpers: wave-uniform broadcast without LDS ----
__device__ __forceinline__ unsigned rl_u32(unsigned v, int j) {
    return (unsigned)__builtin_amdgcn_readlane((int)v, j);
}
__device__ __forceinline__ float rl_f32(float v, int j) {
    return __uint_as_float((unsigned)__builtin_amdgcn_readlane(__float_as_int(v), j));
}

// Accumulate ranks of this lane's 3 keys against a 64-lane key chunk streamed
// via readlane (keys unique -> strict u64 < == exact stable argsort).
__device__ __forceinline__ void rank_accum(
    unsigned kh, unsigned kl, int cnt,
    unsigned long long key0, unsigned long long key1, unsigned long long key2,
    int& r0, int& r1, int& r2)
{
#pragma unroll 4
    for (int j = 0; j < cnt; ++j) {
        const unsigned long long kj =
            ((unsigned long long)rl_u32(kh, j) << 32) | rl_u32(kl, j);
        r0 += (kj < key0);
        r1 += (kj < key1);
        r2 += (kj < key2);
    }
}

// One sorted-order section (<=64 slots held lane-major in nxreg/ofreg).
// Per slot k: s (chained), nxt = readlane(nxreg,k), wq row = readlane(ofreg,k),
// gather wql[off+lane], cumsums, IEEE div, masks in reference order.
// First valid spike == min (windows non-overlapping increasing) -> done flag.
// Returns true when the whole wave is finished.
__device__ __forceinline__ bool scan_section(
    float nxreg, unsigned ofreg, int cnt, const float* __restrict__ wqlane,
    float& s, float& ws, float& iws, float& mn, bool& done)
{
#pragma clang fp contract(off)
    for (int j0 = 0; j0 < cnt; j0 += 8) {
        if (s >= MAX_SPIKE) return true;      // sorted: rest contribute 100
        float nx[8]; const float* wp[8];
#pragma unroll
        for (int u = 0; u < 8; ++u) {
            nx[u] = rl_f32(nxreg, j0 + u);
            wp[u] = wqlane + rl_u32(ofreg, j0 + u);
        }
        float su[8], wsu[8], iwsu[8];
#pragma unroll
        for (int u = 0; u < 8; ++u) {
            su[u] = (u == 0) ? s : nx[u - 1];
            const float wvv = *wp[u];          // lane-consecutive: conflict-free
            ws += wvv;
            const float prod = su[u] * wvv;    // separate rounding (no FMA)
            iws += prod;
            wsu[u]  = ws;
            iwsu[u] = iws;
        }
        s = nx[7];
        // wq >= 0 => ws monotone: batch all-masked if last ws < 1 everywhere.
        if (!__all(wsu[7] < 1.0f)) {
#pragma unroll
            for (int u = 0; u < 8; ++u) {
                const float d = fmaxf(wsu[u] - 1.0f, 1e-10f); // upper clamp never binds
                const float q = iwsu[u] / d;                  // IEEE f32 divide
                const bool valid = (wsu[u] >= 1.0f) & (q >= su[u]) & (q <= nx[u]);
                if (valid & !done) { mn = q; done = true; }
            }
            if (__all(done)) return true;
        }
    }
    return false;
}

// ---------------------------------------------------------------------------
// Spike conv v6: 8 pixels / 512-thread block (1 wave/pixel, 1 lane/out-chan).
// vs v5 (math identical, bit-exact): ALL wave-uniform LDS traffic replaced by
// register broadcast (v_readlane):
//   - sort keys live in VGPRs; 144-step rank stream = 2 readlane + 3 u64-cmp
//     per step, ZERO LDS ops (was 72 broadcast ds_read_b128 per wave)
//   - records: one LDS scatter (3 ds_write_b64) + one lane-spread readback
//     (3 ds_read_b64); nxt chain built with 6 shuffles; scan fetches
//     (nxt, off) via readlane (was 4 broadcast b128 per batch)
//   - only remaining hot LDS op: the per-lane wql gather (1 b32/slot)
// wq staged async via global_load_lds width=16; ONE barrier before the scan
// (wql visibility + vmcnt drain).
// ---------------------------------------------------------------------------
__global__ __launch_bounds__(NTHR, 4) void spike_conv_kernel(
    const float* __restrict__ inp,   // (4,16,32,32)
    const float* __restrict__ wq,    // (144,64)
    float* __restrict__ out)         // (4,64,32,32)
{
#pragma clang fp contract(off)
    __shared__ __align__(16) float wql[F_IN * F_OUT];          // 36 KB
    __shared__ __align__(16) unsigned long long kr[PPB][192];  // 12 KB scatter buf

    const int tid  = threadIdx.x;
    const int lane = tid & 63;
    const int wv_i = tid >> 6;                   // wave id = pixel-in-block
    const int p    = blockIdx.x * PPB + wv_i;    // pixel id
    const int b    = p >> 10;
    const int l    = p & 1023;
    const int h    = l >> 5;
    const int w    = l & 31;

    // ---- async stage wq -> LDS: 36 chunks of 1 KB (64 lanes x 16 B) ----
    for (int c = wv_i; c < 36; c += PPB) {
        const float* g = wq + c * 256 + lane * 4;
        __builtin_amdgcn_global_load_lds(
            (const __attribute__((address_space(1))) void*)g,
            (__attribute__((address_space(3))) void*)&wql[c * 256],
            16, 0, 0);
    }

    // ---- stage patch into registers, build u64 keys (f = c*9 + kh*3 + kw) ----
    float vv[3];
    unsigned long long key[3];
    unsigned khi[3], klo[3];
#pragma unroll
    for (int m = 0; m < 3; ++m) {
        const int i = lane + 64 * m;
        float v = MAX_SPIKE;
        if (i < F_IN) {
            const int c  = i / 9;
            const int r  = i - c * 9;
            const int kh = r / 3;
            const int kw = r - kh * 3;
            const int hh = h + kh - 1;
            const int ww = w + kw - 1;
            float x = 0.f;
            if (hh >= 0 && hh < H_IMG && ww >= 0 && ww < W_IMG)
                x = inp[((b * 16 + c) * H_IMG + hh) * W_IMG + ww];
            v = (x < 0.1f) ? MAX_SPIKE : x;
        }
        vv[m] = v;
        const unsigned bits = __float_as_uint(v);
        key[m] = ((unsigned long long)bits << 8) | (unsigned)i;
        khi[m] = (unsigned)(key[m] >> 32);
        klo[m] = (unsigned)key[m];
    }

    // ---- rank via readlane streams (no LDS) ----
    int r0 = 0, r1 = 0, r2 = 0;
    rank_accum(khi[0], klo[0], 64, key[0], key[1], key[2], r0, r1, r2);
    rank_accum(khi[1], klo[1], 64, key[0], key[1], key[2], r0, r1, r2);
    rank_accum(khi[2], klo[2], 16, key[0], key[1], key[2], r0, r1, r2);

    // ---- scatter (valbits, wq-row word offset) by rank; wave-private ----
    {
        unsigned long long* kb = &kr[wv_i][0];
        kb[r0] = ((unsigned long long)__float_as_uint(vv[0]) << 32)
                 | ((unsigned)lane << 6);
        kb[r1] = ((unsigned long long)__float_as_uint(vv[1]) << 32)
                 | ((unsigned)(lane + 64) << 6);
        if (lane < F_IN - 128)
            kb[r2] = ((unsigned long long)__float_as_uint(vv[2]) << 32)
                     | ((unsigned)(lane + 128) << 6);
    }

    // ---- lane-spread readback: lane i holds slots i, i+64, i+128 ----
    // (same-wave DS ordering is in-order -> no barrier needed)
    const unsigned long long rc0 = kr[wv_i][lane];
    const unsigned long long rc1 = kr[wv_i][lane + 64];
    const unsigned long long rc2 = kr[wv_i][lane + 128];  // lanes>=16: garbage, never broadcast
    const float    sv0 = __uint_as_float((unsigned)(rc0 >> 32));
    const float    sv1 = __uint_as_float((unsigned)(rc1 >> 32));
    const float    sv2 = __uint_as_float((unsigned)(rc2 >> 32));
    const unsigned of0 = (unsigned)rc0;
    const unsigned of1 = (unsigned)rc1;
    const unsigned of2 = (unsigned)rc2;

    // ---- nxt chain: slot k's next sorted value (sentinel 1.0f after 143) ----
    const int nlane = (lane + 1) & 63;
    float nx0 = __shfl(sv0, nlane);
    float nx1 = __shfl(sv1, nlane);
    float nx2 = __shfl(sv2, nlane);
    const float c1 = __shfl(sv1, 0);
    const float c2 = __shfl(sv2, 0);
    if (lane == 63) { nx0 = c1; nx1 = c2; }
    if (lane == 15) { nx2 = 1.0f; }           // slot 143 -> causality sentinel

    float s = __shfl(sv0, 0);                  // sorted val[0]

    // ONE block barrier: wql visible to all waves + async vmcnt drained.
    __syncthreads();

    // ---- scan: first valid spike == min ----
    const float* wqlane = wql + lane;
    float ws  = 0.f;
    float iws = 0.f;
    float mn  = MAX_SPIKE;      // masked / never-valid lanes => exactly 100
    bool  done = false;
    bool fin;
    fin = scan_section(nx0, of0, 64, wqlane, s, ws, iws, mn, done);
    if (!fin) fin = scan_section(nx1, of1, 64, wqlane, s, ws, iws, mn, done);
    if (!fin) scan_section(nx2, of2, 16, wqlane, s, ws, iws, mn, done);

    out[(b * F_OUT + lane) * 1024 + l] = mn;
}

extern "C" void kernel_launch(void* const* d_in, const int* in_sizes, int n_in,
                              void* d_out, int out_size, void* d_ws, size_t ws_size,
                              hipStream_t stream) {
    const float* inp = (const float*)d_in[0];   // 65536 elems
    const float* w   = (const float*)d_in[1];   // 9216 elems
    float* out = (float*)d_out;                 // 262144 elems
    float* wqT = (float*)d_ws;                  // 9216 floats scratch

    quant_fused_kernel<<<36, 256, 0, stream>>>(w, wqT);
    spike_conv_kernel<<<NPIX / PPB, NTHR, 0, stream>>>(inp, wqT, out);
}